// Round 1
// baseline (430.993 us; speedup 1.0000x reference)
//
#include <hip/hip_runtime.h>
#include <hip/hip_bf16.h>
#include <math.h>

#define B_ 8
#define L_ 1024
#define D_ 256
#define H_ 8
#define HD_ 32
#define INNER_ 1024
#define M_ (B_ * L_)  // 8192

// ---------------------------------------------------------------------------
// Tiled f32 GEMM: C[M,N] = A[M,K] @ W[N,K]^T + bias, with fused epilogues.
// EPI: 0 = plain+bias, 1 = bias+erf-GELU, 2 = bias+residual, 3 = bias+scatter
//      to q/k/v layout [B,H,L,HD].
// 64x64 tile, BK=32, 256 threads, 4x4 acc per thread.
// ---------------------------------------------------------------------------
template <int EPI>
__global__ __launch_bounds__(256) void gemm_kernel(
    const float* __restrict__ A, const float* __restrict__ W,
    const float* __restrict__ bias, float* __restrict__ C,
    const float* __restrict__ resid, int M, int N, int K) {
  __shared__ __align__(16) float As[32][68];
  __shared__ __align__(16) float Bs[32][68];
  const int tid = threadIdx.x;
  const int tx = tid & 15, ty = tid >> 4;
  const int m0 = blockIdx.y * 64, n0 = blockIdx.x * 64;
  float acc[4][4] = {};
  for (int k0 = 0; k0 < K; k0 += 32) {
    __syncthreads();
#pragma unroll
    for (int i = 0; i < 8; i++) {
      int idx = tid + i * 256;  // 0..2047 over 64x32 tile
      int r = idx >> 5, c = idx & 31;
      As[c][r] = A[(size_t)(m0 + r) * K + (k0 + c)];
      Bs[c][r] = W[(size_t)(n0 + r) * K + (k0 + c)];
    }
    __syncthreads();
#pragma unroll
    for (int kk = 0; kk < 32; kk++) {
      float4 av = *(const float4*)&As[kk][ty * 4];
      float4 bv = *(const float4*)&Bs[kk][tx * 4];
      float a[4] = {av.x, av.y, av.z, av.w};
      float b[4] = {bv.x, bv.y, bv.z, bv.w};
#pragma unroll
      for (int i = 0; i < 4; i++)
#pragma unroll
        for (int j = 0; j < 4; j++) acc[i][j] = fmaf(a[i], b[j], acc[i][j]);
    }
  }
#pragma unroll
  for (int i = 0; i < 4; i++) {
    int m = m0 + ty * 4 + i;
#pragma unroll
    for (int j = 0; j < 4; j++) {
      int n = n0 + tx * 4 + j;
      float x = acc[i][j] + bias[n];
      if (EPI == 1) x = x * 0.5f * (1.0f + erff(x * 0.70710678118654752f));
      if (EPI == 2) x += resid[(size_t)m * N + n];
      if (EPI == 3) {
        int bb = m >> 10, l = m & 1023, h = n >> 5, d = n & 31;
        C[((((size_t)bb * H_ + h) * L_ + l) << 5) + d] = x;
      } else {
        C[(size_t)m * N + n] = x;
      }
    }
  }
}

// ---------------------------------------------------------------------------
// c = mag*cos(phi), s = mag*sin(phi)   (physics rank-2 decomposition)
// ---------------------------------------------------------------------------
__global__ void cs_kernel(const float* __restrict__ phi,
                          const float* __restrict__ mag, float* __restrict__ c,
                          float* __restrict__ s) {
  int i = blockIdx.x * 256 + threadIdx.x;  // exactly B*H*L = 65536
  float p = phi[i], m = mag[i];
  c[i] = m * cosf(p);
  s[i] = m * sinf(p);
}

// ---------------------------------------------------------------------------
// Flash-style attention, f32. One thread = one query row (partial), 4-way
// key split per row for occupancy; online softmax; merge via LDS.
// q,k,v: [B,H,L,32]; ctx out: [B,L,D]
// grid = (L/64, B*H), block = 256
// ---------------------------------------------------------------------------
__global__ __launch_bounds__(256) void attn_kernel(
    const float* __restrict__ qg, const float* __restrict__ kg,
    const float* __restrict__ vg, const float* __restrict__ cbuf,
    const float* __restrict__ sbuf, const float* __restrict__ mask,
    const float* __restrict__ gamma, float* __restrict__ ctx) {
  __shared__ __align__(16) float smem[8576];  // Ks 4096 | Vs 4096 | c 128 | s 128 | m 128
  float* Ks = smem;
  float* Vs = smem + 4096;
  float* cst = smem + 8192;
  float* sst = smem + 8320;
  float* mst = smem + 8448;

  const int tid = threadIdx.x;
  const int qi = tid & 63;   // query within block
  const int sp = tid >> 6;   // key-split 0..3
  const int bh = blockIdx.y;
  const int b = bh >> 3, h = bh & 7;
  const int l = blockIdx.x * 64 + qi;
  const size_t base = (size_t)bh * L_;

  const float g = gamma[h];
  float qreg[32];
  const float* qp = qg + (base + l) * 32;
#pragma unroll
  for (int d = 0; d < 32; d++) qreg[d] = qp[d] * 0.17677669529663687f;  // 1/sqrt(32)
  const float myc = g * cbuf[base + l];
  const float mys = g * sbuf[base + l];

  float m = -1e30f, lsum = 0.0f;
  float acc[32] = {};

  for (int t = 0; t < 8; t++) {  // 8 tiles of 128 keys
    const int j0 = t * 128;
    __syncthreads();
#pragma unroll
    for (int i = 0; i < 16; i++) {
      int idx = tid + i * 256;  // 0..4095
      Ks[idx] = kg[(base + j0) * 32 + idx];
      Vs[idx] = vg[(base + j0) * 32 + idx];
    }
    if (tid < 128) {
      cst[tid] = cbuf[base + j0 + tid];
      sst[tid] = sbuf[base + j0 + tid];
      mst[tid] = mask[(size_t)b * L_ + j0 + tid];
    }
    __syncthreads();
    const int jj0 = sp * 32;
    for (int j = jj0; j < jj0 + 32; j++) {
      float sc = myc * cst[j] + mys * sst[j] + mst[j];
      const float* kr = Ks + j * 32;
#pragma unroll
      for (int d = 0; d < 32; d++) sc = fmaf(qreg[d], kr[d], sc);
      if (sc > m) {
        float r = __expf(m - sc);
        lsum *= r;
#pragma unroll
        for (int d = 0; d < 32; d++) acc[d] *= r;
        m = sc;
      }
      float p = __expf(sc - m);
      lsum += p;
      const float* vr = Vs + j * 32;
#pragma unroll
      for (int d = 0; d < 32; d++) acc[d] = fmaf(p, vr[d], acc[d]);
    }
  }

  // merge the 4 splits
  __syncthreads();
  if (sp > 0) {
    float* dst = smem + ((size_t)(sp - 1) * 64 + qi) * 34;
    dst[0] = m;
    dst[1] = lsum;
#pragma unroll
    for (int d = 0; d < 32; d++) dst[2 + d] = acc[d];
  }
  __syncthreads();
  if (sp == 0) {
    for (int s2 = 0; s2 < 3; s2++) {
      const float* src = smem + ((size_t)s2 * 64 + qi) * 34;
      float m2 = src[0], l2 = src[1];
      float mn = fmaxf(m, m2);
      float r1 = __expf(m - mn), r2 = __expf(m2 - mn);
      lsum = lsum * r1 + l2 * r2;
#pragma unroll
      for (int d = 0; d < 32; d++) acc[d] = acc[d] * r1 + src[2 + d] * r2;
      m = mn;
    }
    float inv = 1.0f / lsum;
    float* op = ctx + ((size_t)b * L_ + l) * D_ + h * 32;
#pragma unroll
    for (int d = 0; d < 32; d++) op[d] = acc[d] * inv;
  }
}

// ---------------------------------------------------------------------------
// LayerNorm over D=256 per row. One block (256 threads) per row.
// ---------------------------------------------------------------------------
__global__ __launch_bounds__(256) void ln_kernel(const float* __restrict__ x,
                                                 const float* __restrict__ g,
                                                 const float* __restrict__ b,
                                                 float* __restrict__ y) {
  const int row = blockIdx.x, t = threadIdx.x;
  const float v = x[(size_t)row * 256 + t];
  float s1 = v, s2 = v * v;
#pragma unroll
  for (int o = 1; o < 64; o <<= 1) {
    s1 += __shfl_xor(s1, o, 64);
    s2 += __shfl_xor(s2, o, 64);
  }
  __shared__ float w1[4], w2[4];
  if ((t & 63) == 0) {
    w1[t >> 6] = s1;
    w2[t >> 6] = s2;
  }
  __syncthreads();
  float ts1 = w1[0] + w1[1] + w1[2] + w1[3];
  float ts2 = w2[0] + w2[1] + w2[2] + w2[3];
  float mean = ts1 * (1.0f / 256.0f);
  float var = fmaxf(ts2 * (1.0f / 256.0f) - mean * mean, 0.0f);
  y[(size_t)row * 256 + t] = (v - mean) * rsqrtf(var + 1e-12f) * g[t] + b[t];
}

// ---------------------------------------------------------------------------
extern "C" void kernel_launch(void* const* d_in, const int* in_sizes, int n_in,
                              void* d_out, int out_size, void* d_ws,
                              size_t ws_size, hipStream_t stream) {
  const float* hs = (const float*)d_in[0];
  const float* mask = (const float*)d_in[1];
  const float* phi = (const float*)d_in[2];
  const float* mag = (const float*)d_in[3];
  const float* Wq = (const float*)d_in[4];
  const float* bq = (const float*)d_in[5];
  const float* Wk = (const float*)d_in[6];
  const float* bk = (const float*)d_in[7];
  const float* Wv = (const float*)d_in[8];
  const float* bv = (const float*)d_in[9];
  const float* Wo = (const float*)d_in[10];
  const float* bo = (const float*)d_in[11];
  const float* ln1g = (const float*)d_in[12];
  const float* ln1b = (const float*)d_in[13];
  const float* gamma = (const float*)d_in[14];
  const float* W1 = (const float*)d_in[15];
  const float* b1 = (const float*)d_in[16];
  const float* W2 = (const float*)d_in[17];
  const float* b2 = (const float*)d_in[18];
  const float* ln2g = (const float*)d_in[19];
  const float* ln2b = (const float*)d_in[20];

  float* ws = (float*)d_ws;
  float* qb = ws + 0;         // [B,H,L,32]  2M floats
  float* kb = ws + 2097152;   // 2M
  float* vb = ws + 4194304;   // 2M
  float* cb = ws + 6291456;   // 64K
  float* sb = ws + 6356992;   // 64K
  float* ctx = ws + 6422528;  // [B,L,D] 2M
  float* tmp = ws + 8519680;  // pre-LN1, 2M
  float* aout = ws + 10616832;  // attn_out, 2M (kept)
  float* hmid = ws + 0;         // FFN mid [8192,1024], 8M (reuses q/k/v/ctx)
  float* tmp2 = ws + 8519680;   // pre-LN2 (reuses tmp)

  dim3 blk(256);
  // QKV projections (scatter to [B,H,L,32])
  gemm_kernel<3><<<dim3(4, 128), blk, 0, stream>>>(hs, Wq, bq, qb, nullptr, M_, D_, D_);
  gemm_kernel<3><<<dim3(4, 128), blk, 0, stream>>>(hs, Wk, bk, kb, nullptr, M_, D_, D_);
  gemm_kernel<3><<<dim3(4, 128), blk, 0, stream>>>(hs, Wv, bv, vb, nullptr, M_, D_, D_);
  // physics rank-2 vectors
  cs_kernel<<<dim3(256), blk, 0, stream>>>(phi, mag, cb, sb);
  // fused attention
  attn_kernel<<<dim3(16, 64), blk, 0, stream>>>(qb, kb, vb, cb, sb, mask, gamma, ctx);
  // output projection + residual, then LN1
  gemm_kernel<2><<<dim3(4, 128), blk, 0, stream>>>(ctx, Wo, bo, tmp, hs, M_, D_, D_);
  ln_kernel<<<dim3(8192), blk, 0, stream>>>(tmp, ln1g, ln1b, aout);
  // FFN
  gemm_kernel<1><<<dim3(16, 128), blk, 0, stream>>>(aout, W1, b1, hmid, nullptr, M_, INNER_, D_);
  gemm_kernel<2><<<dim3(4, 128), blk, 0, stream>>>(hmid, W2, b2, tmp2, aout, M_, D_, INNER_);
  ln_kernel<<<dim3(8192), blk, 0, stream>>>(tmp2, ln2g, ln2b, (float*)d_out);
}

// Round 2
// 171.169 us; speedup vs baseline: 2.5179x; 2.5179x over previous
//
#include <hip/hip_runtime.h>
#include <hip/hip_bf16.h>
#include <math.h>

#define B_ 8
#define L_ 1024
#define D_ 256
#define H_ 8
#define INNER_ 1024
#define M_ 8192

typedef __attribute__((ext_vector_type(8))) short bf16x8;
typedef __attribute__((ext_vector_type(4))) float f32x4;

__device__ __forceinline__ unsigned short f2bf(float f) {
  union { float f; unsigned u; } v; v.f = f;
  unsigned r = v.u + 0x7fffu + ((v.u >> 16) & 1u);
  return (unsigned short)(r >> 16);
}
__device__ __forceinline__ unsigned pack2(float lo, float hi) {
  return (unsigned)f2bf(lo) | ((unsigned)f2bf(hi) << 16);
}

// ---------------------------------------------------------------------------
// Fused QKV GEMM (bf16 MFMA). A=hs f32 [8192,256], W f32 [256,256].
// Q: (acc+bias)*1/sqrt(32) -> qb [B,H,L,32] bf16
// K: acc+bias             -> kb [B,H,L,32] bf16
// V: acc+bias             -> vt [B,H,32,L] bf16 (transposed)
// grid (6, 64): x = mat*2 + nblock
// ---------------------------------------------------------------------------
__global__ __launch_bounds__(256) void gemm_qkv(
    const float* __restrict__ A, const float* __restrict__ Wq,
    const float* __restrict__ Wk, const float* __restrict__ Wv,
    const float* __restrict__ bq, const float* __restrict__ bk,
    const float* __restrict__ bv, unsigned short* __restrict__ qb,
    unsigned short* __restrict__ kb, unsigned short* __restrict__ vt) {
  __shared__ __align__(16) unsigned short As[128 * 64];
  __shared__ __align__(16) unsigned short Bs[128 * 64];
  const int tid = threadIdx.x;
  const int mat = blockIdx.x >> 1;
  const int n0 = (blockIdx.x & 1) * 128;
  const int m0 = blockIdx.y * 128;
  const float* W = (mat == 0) ? Wq : ((mat == 1) ? Wk : Wv);
  const float* bias = (mat == 0) ? bq : ((mat == 1) ? bk : bv);
  const int wm = (tid >> 7) & 1, wn = (tid >> 6) & 1;
  const int g = (tid >> 4) & 3, c = tid & 15;
  f32x4 acc[4][4] = {};
  for (int k0 = 0; k0 < 256; k0 += 64) {
    __syncthreads();
#pragma unroll
    for (int i = 0; i < 8; i++) {
      int idx = tid * 4 + i * 1024;
      int r = idx >> 6, c4 = idx & 63;
      float4 va = *(const float4*)&A[(size_t)(m0 + r) * 256 + k0 + c4];
      float4 vb = *(const float4*)&W[(size_t)(n0 + r) * 256 + k0 + c4];
      int dst = r * 64 + (((c4 >> 3) ^ (r & 7)) << 3) + ((c4 >> 2) & 1) * 4;
      *(uint2*)&As[dst] = make_uint2(pack2(va.x, va.y), pack2(va.z, va.w));
      *(uint2*)&Bs[dst] = make_uint2(pack2(vb.x, vb.y), pack2(vb.z, vb.w));
    }
    __syncthreads();
#pragma unroll
    for (int kk = 0; kk < 2; kk++) {
      bf16x8 af[4], bfr[4];
#pragma unroll
      for (int mi = 0; mi < 4; mi++) {
        int row = wm * 64 + mi * 16 + c;
        af[mi] = *(const bf16x8*)&As[row * 64 + (((g + 4 * kk) ^ (row & 7)) << 3)];
      }
#pragma unroll
      for (int ni = 0; ni < 4; ni++) {
        int row = wn * 64 + ni * 16 + c;
        bfr[ni] = *(const bf16x8*)&Bs[row * 64 + (((g + 4 * kk) ^ (row & 7)) << 3)];
      }
#pragma unroll
      for (int mi = 0; mi < 4; mi++)
#pragma unroll
        for (int ni = 0; ni < 4; ni++)
          acc[mi][ni] = __builtin_amdgcn_mfma_f32_16x16x32_bf16(af[mi], bfr[ni], acc[mi][ni], 0, 0, 0);
    }
  }
  const float scale = (mat == 0) ? 0.17677669529663687f : 1.0f;
#pragma unroll
  for (int ni = 0; ni < 4; ni++) {
    int n = n0 + wn * 64 + ni * 16 + c;
    float bv_ = bias[n];
    int h = n >> 5, d = n & 31;
#pragma unroll
    for (int mi = 0; mi < 4; mi++) {
      int mbase = m0 + wm * 64 + mi * 16 + 4 * g;
      int b = mbase >> 10, l = mbase & 1023;
      if (mat < 2) {
        unsigned short* out = (mat == 0) ? qb : kb;
#pragma unroll
        for (int r = 0; r < 4; r++)
          out[((((size_t)b * 8 + h) * 1024 + (l + r)) << 5) + d] =
              f2bf((acc[mi][ni][r] + bv_) * scale);
      } else {
        uint2 w2;
        w2.x = pack2(acc[mi][ni][0] + bv_, acc[mi][ni][1] + bv_);
        w2.y = pack2(acc[mi][ni][2] + bv_, acc[mi][ni][3] + bv_);
        *(uint2*)&vt[(((size_t)b * 8 + h) * 32 + d) * 1024 + l] = w2;
      }
    }
  }
}

// ---------------------------------------------------------------------------
// Generic bf16-MFMA GEMM with epilogue. C = A @ W^T.
// EPI=1: f32 out = acc + bias + resid      (Wo, FFN2)
// EPI=2: bf16 out = gelu_erf(acc + bias)   (FFN1)
// ---------------------------------------------------------------------------
template <int EPI, typename TA>
__global__ __launch_bounds__(256) void gemm_epi(
    const TA* __restrict__ A, const float* __restrict__ W,
    const float* __restrict__ bias, const float* __restrict__ resid,
    void* __restrict__ Cout, int N, int K) {
  __shared__ __align__(16) unsigned short As[128 * 64];
  __shared__ __align__(16) unsigned short Bs[128 * 64];
  const int tid = threadIdx.x;
  const int n0 = blockIdx.x * 128;
  const int m0 = blockIdx.y * 128;
  const int wm = (tid >> 7) & 1, wn = (tid >> 6) & 1;
  const int g = (tid >> 4) & 3, c = tid & 15;
  f32x4 acc[4][4] = {};
  for (int k0 = 0; k0 < K; k0 += 64) {
    __syncthreads();
    if constexpr (sizeof(TA) == 4) {
#pragma unroll
      for (int i = 0; i < 8; i++) {
        int idx = tid * 4 + i * 1024;
        int r = idx >> 6, c4 = idx & 63;
        float4 va = *(const float4*)&A[(size_t)(m0 + r) * K + k0 + c4];
        int dst = r * 64 + (((c4 >> 3) ^ (r & 7)) << 3) + ((c4 >> 2) & 1) * 4;
        *(uint2*)&As[dst] = make_uint2(pack2(va.x, va.y), pack2(va.z, va.w));
      }
    } else {
#pragma unroll
      for (int i = 0; i < 4; i++) {
        int idx = tid * 8 + i * 2048;
        int r = idx >> 6, c8 = idx & 63;
        bf16x8 v = *(const bf16x8*)&A[(size_t)(m0 + r) * K + k0 + c8];
        *(bf16x8*)&As[r * 64 + (((c8 >> 3) ^ (r & 7)) << 3)] = v;
      }
    }
#pragma unroll
    for (int i = 0; i < 8; i++) {
      int idx = tid * 4 + i * 1024;
      int r = idx >> 6, c4 = idx & 63;
      float4 vb = *(const float4*)&W[(size_t)(n0 + r) * K + k0 + c4];
      int dst = r * 64 + (((c4 >> 3) ^ (r & 7)) << 3) + ((c4 >> 2) & 1) * 4;
      *(uint2*)&Bs[dst] = make_uint2(pack2(vb.x, vb.y), pack2(vb.z, vb.w));
    }
    __syncthreads();
#pragma unroll
    for (int kk = 0; kk < 2; kk++) {
      bf16x8 af[4], bfr[4];
#pragma unroll
      for (int mi = 0; mi < 4; mi++) {
        int row = wm * 64 + mi * 16 + c;
        af[mi] = *(const bf16x8*)&As[row * 64 + (((g + 4 * kk) ^ (row & 7)) << 3)];
      }
#pragma unroll
      for (int ni = 0; ni < 4; ni++) {
        int row = wn * 64 + ni * 16 + c;
        bfr[ni] = *(const bf16x8*)&Bs[row * 64 + (((g + 4 * kk) ^ (row & 7)) << 3)];
      }
#pragma unroll
      for (int mi = 0; mi < 4; mi++)
#pragma unroll
        for (int ni = 0; ni < 4; ni++)
          acc[mi][ni] = __builtin_amdgcn_mfma_f32_16x16x32_bf16(af[mi], bfr[ni], acc[mi][ni], 0, 0, 0);
    }
  }
#pragma unroll
  for (int ni = 0; ni < 4; ni++) {
    int n = n0 + wn * 64 + ni * 16 + c;
    float bv_ = bias[n];
#pragma unroll
    for (int mi = 0; mi < 4; mi++) {
      int mbase = m0 + wm * 64 + mi * 16 + 4 * g;
#pragma unroll
      for (int r = 0; r < 4; r++) {
        int m = mbase + r;
        float x = acc[mi][ni][r] + bv_;
        if constexpr (EPI == 1) {
          ((float*)Cout)[(size_t)m * N + n] = x + resid[(size_t)m * N + n];
        } else {
          ((unsigned short*)Cout)[(size_t)m * N + n] =
              f2bf(x * 0.5f * (1.0f + erff(x * 0.70710678118654752f)));
        }
      }
    }
  }
}

// ---------------------------------------------------------------------------
// cms: per (b,h,l): (mag*cos(phi), mag*sin(phi), mask[b][l], 0)
// ---------------------------------------------------------------------------
__global__ void cms_kernel(const float* __restrict__ phi,
                           const float* __restrict__ mag,
                           const float* __restrict__ mask,
                           float4* __restrict__ cms) {
  int i = blockIdx.x * 256 + threadIdx.x;  // B*H*L = 65536
  float p = phi[i], mg = mag[i];
  int b = i >> 13, l = i & 1023;
  float sn, cs;
  sincosf(p, &sn, &cs);
  cms[i] = make_float4(mg * cs, mg * sn, mask[b * 1024 + l], 0.0f);
}

// ---------------------------------------------------------------------------
// MFMA flash attention. 4 waves/block, 16 queries/wave, 128-key LDS chunks.
// Swapped QK^T (mfma(K,Q)) -> in-lane softmax -> shuffle-repack P -> PV.
// ---------------------------------------------------------------------------
__global__ __launch_bounds__(256) void attn_kernel(
    const unsigned short* __restrict__ qb, const unsigned short* __restrict__ kb,
    const unsigned short* __restrict__ vt, const float4* __restrict__ cms,
    const float* __restrict__ gamma, unsigned short* __restrict__ ctx) {
  __shared__ __align__(16) unsigned short Ks[4096];  // [128][32] swizzled
  __shared__ __align__(16) unsigned short Vs[4096];  // [32][128] swizzled
  __shared__ __align__(16) float4 cmsS[128];
  const int tid = threadIdx.x;
  const int w = tid >> 6, g = (tid >> 4) & 3, c = tid & 15;
  const int bh = blockIdx.y, b = bh >> 3, h = bh & 7;
  const int qbase = blockIdx.x * 64 + w * 16;
  const size_t kvbase = (size_t)bh * 1024;

  bf16x8 qf = *(const bf16x8*)&qb[(kvbase + qbase + c) * 32 + 8 * g];
  float4 cq = cms[kvbase + qbase + c];
  const float gam = gamma[h];
  const float cq2 = gam * cq.x, sq2 = gam * cq.y;

  float m = 0.0f, lsum = 0.0f;
  f32x4 acc0 = {}, acc1 = {};

  for (int j0 = 0; j0 < 1024; j0 += 128) {
    __syncthreads();
#pragma unroll
    for (int i = 0; i < 2; i++) {  // K [128][32]
      int r = tid >> 1, d0 = (tid & 1) * 16 + i * 8;
      bf16x8 v = *(const bf16x8*)&kb[(kvbase + j0 + r) * 32 + d0];
      *(bf16x8*)&Ks[r * 32 + (((d0 >> 3) ^ ((r >> 1) & 3)) << 3)] = v;
    }
#pragma unroll
    for (int i = 0; i < 2; i++) {  // Vt [32][128]
      int d = tid >> 3, j = (tid & 7) * 16 + i * 8;
      bf16x8 v = *(const bf16x8*)&vt[((size_t)bh * 32 + d) * 1024 + j0 + j];
      *(bf16x8*)&Vs[d * 128 + (((j >> 3) ^ (d & 7)) << 3)] = v;
    }
    if (tid < 128) cmsS[tid] = cms[kvbase + j0 + tid];
    __syncthreads();

    for (int strip = 0; strip < 4; strip++) {
      f32x4 st[2];
#pragma unroll
      for (int t = 0; t < 2; t++) {
        int row = strip * 32 + 16 * t + c;
        bf16x8 kf = *(const bf16x8*)&Ks[row * 32 + ((g ^ ((row >> 1) & 3)) << 3)];
        f32x4 z = {};
        st[t] = __builtin_amdgcn_mfma_f32_16x16x32_bf16(kf, qf, z, 0, 0, 0);
      }
      float sv[8];
#pragma unroll
      for (int t = 0; t < 2; t++)
#pragma unroll
        for (int r = 0; r < 4; r++) {
          float4 km = cmsS[strip * 32 + 16 * t + 4 * g + r];
          sv[t * 4 + r] = st[t][r] + fmaf(cq2, km.x, fmaf(sq2, km.y, km.z));
        }
      float pmax = sv[0];
#pragma unroll
      for (int i = 1; i < 8; i++) pmax = fmaxf(pmax, sv[i]);
      pmax = fmaxf(pmax, __shfl_xor(pmax, 16, 64));
      pmax = fmaxf(pmax, __shfl_xor(pmax, 32, 64));
      if (__any(pmax > m + 8.0f)) {
        float mn = fmaxf(m, pmax);
        float rs = __expf(m - mn);
        lsum *= rs;
        m = mn;
#pragma unroll
        for (int r = 0; r < 4; r++) {
          float rr = __shfl(rs, 4 * g + r, 64);
          acc0[r] *= rr;
          acc1[r] *= rr;
        }
      }
      unsigned pk00, pk01, pk10, pk11;
      {
        float p0 = __expf(sv[0] - m), p1 = __expf(sv[1] - m);
        float p2 = __expf(sv[2] - m), p3 = __expf(sv[3] - m);
        float p4 = __expf(sv[4] - m), p5 = __expf(sv[5] - m);
        float p6 = __expf(sv[6] - m), p7 = __expf(sv[7] - m);
        lsum += ((p0 + p1) + (p2 + p3)) + ((p4 + p5) + (p6 + p7));
        pk00 = pack2(p0, p1); pk01 = pack2(p2, p3);
        pk10 = pack2(p4, p5); pk11 = pack2(p6, p7);
      }
      int s0 = ((tid & 16) << 1) + c;  // 32*(g&1)+c
      int s1 = s0 + 16;
      unsigned q00 = (unsigned)__shfl((int)pk00, s0, 64);
      unsigned q01 = (unsigned)__shfl((int)pk01, s0, 64);
      unsigned q02 = (unsigned)__shfl((int)pk00, s1, 64);
      unsigned q03 = (unsigned)__shfl((int)pk01, s1, 64);
      unsigned q10 = (unsigned)__shfl((int)pk10, s0, 64);
      unsigned q11 = (unsigned)__shfl((int)pk11, s0, 64);
      unsigned q12 = (unsigned)__shfl((int)pk10, s1, 64);
      unsigned q13 = (unsigned)__shfl((int)pk11, s1, 64);
      bool hi = (g >> 1) != 0;
      union { unsigned u[4]; bf16x8 v; } af;
      af.u[0] = hi ? q10 : q00;
      af.u[1] = hi ? q11 : q01;
      af.u[2] = hi ? q12 : q02;
      af.u[3] = hi ? q13 : q03;
#pragma unroll
      for (int td = 0; td < 2; td++) {
        int d = c + 16 * td;
        int slot = strip * 4 + g;
        bf16x8 vf = *(const bf16x8*)&Vs[d * 128 + ((slot ^ (c & 7)) << 3)];
        if (td == 0)
          acc0 = __builtin_amdgcn_mfma_f32_16x16x32_bf16(af.v, vf, acc0, 0, 0, 0);
        else
          acc1 = __builtin_amdgcn_mfma_f32_16x16x32_bf16(af.v, vf, acc1, 0, 0, 0);
      }
    }
  }
  lsum += __shfl_xor(lsum, 16, 64);
  lsum += __shfl_xor(lsum, 32, 64);
  float inv = 1.0f / lsum;
#pragma unroll
  for (int r = 0; r < 4; r++) {
    float ir = __shfl(inv, 4 * g + r, 64);
    unsigned short* op =
        &ctx[((size_t)b * 1024 + qbase + 4 * g + r) * 256 + h * 32 + c];
    op[0] = f2bf(acc0[r] * ir);
    op[16] = f2bf(acc1[r] * ir);
  }
}

// ---------------------------------------------------------------------------
// LayerNorm over D=256 per row (f32).
// ---------------------------------------------------------------------------
__global__ __launch_bounds__(256) void ln_kernel(const float* __restrict__ x,
                                                 const float* __restrict__ g,
                                                 const float* __restrict__ b,
                                                 float* __restrict__ y) {
  const int row = blockIdx.x, t = threadIdx.x;
  const float v = x[(size_t)row * 256 + t];
  float s1 = v, s2 = v * v;
#pragma unroll
  for (int o = 1; o < 64; o <<= 1) {
    s1 += __shfl_xor(s1, o, 64);
    s2 += __shfl_xor(s2, o, 64);
  }
  __shared__ float w1[4], w2[4];
  if ((t & 63) == 0) {
    w1[t >> 6] = s1;
    w2[t >> 6] = s2;
  }
  __syncthreads();
  float ts1 = w1[0] + w1[1] + w1[2] + w1[3];
  float ts2 = w2[0] + w2[1] + w2[2] + w2[3];
  float mean = ts1 * (1.0f / 256.0f);
  float var = fmaxf(ts2 * (1.0f / 256.0f) - mean * mean, 0.0f);
  y[(size_t)row * 256 + t] = (v - mean) * rsqrtf(var + 1e-12f) * g[t] + b[t];
}

// ---------------------------------------------------------------------------
extern "C" void kernel_launch(void* const* d_in, const int* in_sizes, int n_in,
                              void* d_out, int out_size, void* d_ws,
                              size_t ws_size, hipStream_t stream) {
  const float* hs = (const float*)d_in[0];
  const float* mask = (const float*)d_in[1];
  const float* phi = (const float*)d_in[2];
  const float* mag = (const float*)d_in[3];
  const float* Wq = (const float*)d_in[4];
  const float* bq = (const float*)d_in[5];
  const float* Wk = (const float*)d_in[6];
  const float* bk = (const float*)d_in[7];
  const float* Wv = (const float*)d_in[8];
  const float* bv = (const float*)d_in[9];
  const float* Wo = (const float*)d_in[10];
  const float* bo = (const float*)d_in[11];
  const float* ln1g = (const float*)d_in[12];
  const float* ln1b = (const float*)d_in[13];
  const float* gamma = (const float*)d_in[14];
  const float* W1 = (const float*)d_in[15];
  const float* b1 = (const float*)d_in[16];
  const float* W2 = (const float*)d_in[17];
  const float* b2 = (const float*)d_in[18];
  const float* ln2g = (const float*)d_in[19];
  const float* ln2b = (const float*)d_in[20];

  char* wsb = (char*)d_ws;
  unsigned short* qb = (unsigned short*)(wsb + (0ull << 20));    // 4MB
  unsigned short* kb = (unsigned short*)(wsb + (4ull << 20));    // 4MB
  unsigned short* vt = (unsigned short*)(wsb + (8ull << 20));    // 4MB
  float4* cms = (float4*)(wsb + (12ull << 20));                  // 1MB
  unsigned short* ctx = (unsigned short*)(wsb + (13ull << 20));  // 4MB
  float* tmp = (float*)(wsb + (17ull << 20));                    // 8MB
  float* aout = (float*)(wsb + (25ull << 20));                   // 8MB
  unsigned short* hbuf = (unsigned short*)(wsb + (0ull << 20));  // 16MB (reuse)

  dim3 blk(256);
  gemm_qkv<<<dim3(6, 64), blk, 0, stream>>>(hs, Wq, Wk, Wv, bq, bk, bv, qb, kb, vt);
  cms_kernel<<<dim3(256), blk, 0, stream>>>(phi, mag, mask, cms);
  attn_kernel<<<dim3(16, 64), blk, 0, stream>>>(qb, kb, vt, cms, gamma, ctx);
  gemm_epi<1, unsigned short><<<dim3(2, 64), blk, 0, stream>>>(ctx, Wo, bo, hs, tmp, 256, 256);
  ln_kernel<<<dim3(8192), blk, 0, stream>>>(tmp, ln1g, ln1b, aout);
  gemm_epi<2, float><<<dim3(8, 64), blk, 0, stream>>>(aout, W1, b1, nullptr, hbuf, 1024, 256);
  gemm_epi<1, unsigned short><<<dim3(2, 64), blk, 0, stream>>>(hbuf, W2, b2, aout, tmp, 256, 1024);
  ln_kernel<<<dim3(8192), blk, 0, stream>>>(tmp, ln2g, ln2b, (float*)d_out);
}

// Round 3
// 117.589 us; speedup vs baseline: 3.6653x; 1.4557x over previous
//
#include <hip/hip_runtime.h>
#include <hip/hip_bf16.h>
#include <math.h>

typedef __attribute__((ext_vector_type(8))) short bf16x8;
typedef __attribute__((ext_vector_type(4))) float f32x4;
typedef __attribute__((ext_vector_type(16))) float f32x16;

__device__ __forceinline__ unsigned short f2bf(float f) {
  union { float f; unsigned u; } v; v.f = f;
  unsigned r = v.u + 0x7fffu + ((v.u >> 16) & 1u);
  return (unsigned short)(r >> 16);
}
__device__ __forceinline__ unsigned pack2(float lo, float hi) {
  return (unsigned)f2bf(lo) | ((unsigned)f2bf(hi) << 16);
}
__device__ __forceinline__ float bf2f(unsigned short u) {
  union { unsigned u; float f; } v; v.u = ((unsigned)u) << 16; return v.f;
}
__device__ __forceinline__ float fexp2(float x) {
#if __has_builtin(__builtin_amdgcn_exp2f)
  return __builtin_amdgcn_exp2f(x);
#else
  return exp2f(x);
#endif
}
__device__ __forceinline__ unsigned cvtpk(float lo, float hi) {
  unsigned r;
  asm("v_cvt_pk_bf16_f32 %0, %1, %2" : "=v"(r) : "v"(lo), "v"(hi));
  return r;
}
#if __has_builtin(__builtin_amdgcn_permlane32_swap)
typedef __attribute__((ext_vector_type(2))) unsigned u32x2;
__device__ __forceinline__ void plswap(unsigned& a, unsigned& b) {
  u32x2 r = __builtin_amdgcn_permlane32_swap(a, b, false, false);
  a = r[0]; b = r[1];
}
#else
__device__ __forceinline__ void plswap(unsigned& a, unsigned& b) {
  unsigned as = (unsigned)__shfl_xor((int)a, 32, 64);
  unsigned bs = (unsigned)__shfl_xor((int)b, 32, 64);
  bool hi = (threadIdx.x & 32) != 0;
  unsigned na = hi ? bs : a;
  unsigned nb = hi ? b : as;
  a = na; b = nb;
}
#endif

#define L2E 1.4426950408889634f

// ---------------------------------------------------------------------------
// prep: weight f32->bf16, hs f32->bf16, and physics ext-slab fills.
// grid 2048 x 256
// ---------------------------------------------------------------------------
__global__ __launch_bounds__(256) void prep_kernel(
    const float* __restrict__ hs, const float* __restrict__ phi,
    const float* __restrict__ mag, const float* __restrict__ mask,
    const float* __restrict__ gamma, const float* __restrict__ Wq,
    const float* __restrict__ Wk, const float* __restrict__ Wv,
    const float* __restrict__ Wo, const float* __restrict__ W1,
    const float* __restrict__ W2, unsigned short* __restrict__ wts,
    unsigned short* __restrict__ hsb, unsigned short* __restrict__ qx,
    unsigned short* __restrict__ kx) {
  const int blk = blockIdx.x, tid = threadIdx.x;
  if (blk < 768) {  // weights: 786432 elems, 4/thread
    int i = blk * 1024 + tid * 4;
    const float* src; int off;
    if (i < 262144) {
      src = (i < 131072) ? (i < 65536 ? Wq : Wk) : (i < 196608 ? Wv : Wo);
      off = i & 65535;
    } else if (i < 524288) { src = W1; off = i - 262144; }
    else { src = W2; off = i - 524288; }
    float4 v = *(const float4*)&src[off];
    *(uint2*)&wts[i] = make_uint2(pack2(v.x, v.y), pack2(v.z, v.w));
  } else if (blk < 1792) {  // hs: 2097152 elems, 8/thread
    int i = (blk - 768) * 2048 + tid * 8;
    const float4* hp = (const float4*)hs;
    float4 a = hp[i >> 2], b = hp[(i >> 2) + 1];
    uint4 o = make_uint4(pack2(a.x, a.y), pack2(a.z, a.w), pack2(b.x, b.y),
                         pack2(b.z, b.w));
    *(uint4*)&hsb[i] = o;
  } else {  // ext slabs: 65536 rows
    int row = (blk - 1792) * 256 + tid;
    int bh = row >> 10, key = row & 1023, b = row >> 13, h = (row >> 10) & 7;
    float p = phi[row], mg = mag[row];
    float sn, cs; sincosf(p, &sn, &cs);
    float c = mg * cs, s = mg * sn;
    float msk = mask[b * 1024 + key];
    int ch = key >> 5, k32 = key & 31;
    size_t base = ((((size_t)(bh * 32 + ch) * 3 + 2) * 2 + 0) * 32 + k32) * 8;
    *(uint4*)&kx[base] = make_uint4(pack2(c, s), pack2(msk, 0.0f), 0u, 0u);
    *(uint4*)&kx[base + 256] = make_uint4(0u, 0u, 0u, 0u);
    float g = gamma[h];
    *(uint4*)&qx[base] = make_uint4(pack2(L2E * g * c, L2E * g * s),
                                    pack2(L2E, 0.0f), 0u, 0u);
    *(uint4*)&qx[base + 256] = make_uint4(0u, 0u, 0u, 0u);
  }
}

// ---------------------------------------------------------------------------
// Fused QKV GEMM (bf16 in, bf16 MFMA). Writes fragment-order qx/kx/vt2.
// grid (6, 64): x = mat*2 + nblock. A=hsb [8192,256], W=wts bf16 [256,256].
// ---------------------------------------------------------------------------
__global__ __launch_bounds__(256) void gemm_qkv(
    const unsigned short* __restrict__ A, const unsigned short* __restrict__ wts,
    const float* __restrict__ bq, const float* __restrict__ bk,
    const float* __restrict__ bv, unsigned short* __restrict__ qx,
    unsigned short* __restrict__ kx, unsigned short* __restrict__ vt2) {
  __shared__ __align__(16) unsigned short As[128 * 64];
  __shared__ __align__(16) unsigned short Bs[128 * 64];
  const int tid = threadIdx.x;
  const int mat = blockIdx.x >> 1;
  const int n0 = (blockIdx.x & 1) * 128;
  const int m0 = blockIdx.y * 128;
  const unsigned short* W = wts + mat * 65536;
  const float* bias = (mat == 0) ? bq : ((mat == 1) ? bk : bv);
  const int wm = (tid >> 7) & 1, wn = (tid >> 6) & 1;
  const int g = (tid >> 4) & 3, c = tid & 15;
  f32x4 acc[4][4] = {};
  for (int k0 = 0; k0 < 256; k0 += 64) {
    __syncthreads();
#pragma unroll
    for (int i = 0; i < 4; i++) {
      int idx = tid * 8 + i * 2048;
      int r = idx >> 6, c8 = idx & 63;
      bf16x8 va = *(const bf16x8*)&A[(size_t)(m0 + r) * 256 + k0 + c8];
      bf16x8 vb = *(const bf16x8*)&W[(size_t)(n0 + r) * 256 + k0 + c8];
      int dst = r * 64 + (((c8 >> 3) ^ (r & 7)) << 3);
      *(bf16x8*)&As[dst] = va;
      *(bf16x8*)&Bs[dst] = vb;
    }
    __syncthreads();
#pragma unroll
    for (int kk = 0; kk < 2; kk++) {
      bf16x8 af[4], bfr[4];
#pragma unroll
      for (int mi = 0; mi < 4; mi++) {
        int row = wm * 64 + mi * 16 + c;
        af[mi] = *(const bf16x8*)&As[row * 64 + (((g + 4 * kk) ^ (row & 7)) << 3)];
      }
#pragma unroll
      for (int ni = 0; ni < 4; ni++) {
        int row = wn * 64 + ni * 16 + c;
        bfr[ni] = *(const bf16x8*)&Bs[row * 64 + (((g + 4 * kk) ^ (row & 7)) << 3)];
      }
#pragma unroll
      for (int mi = 0; mi < 4; mi++)
#pragma unroll
        for (int ni = 0; ni < 4; ni++)
          acc[mi][ni] = __builtin_amdgcn_mfma_f32_16x16x32_bf16(af[mi], bfr[ni], acc[mi][ni], 0, 0, 0);
    }
  }
  const float scale = (mat == 0) ? (L2E * 0.17677669529663687f) : 1.0f;
#pragma unroll
  for (int ni = 0; ni < 4; ni++) {
    int n = n0 + wn * 64 + ni * 16 + c;
    float bv_ = bias[n];
    int h = n >> 5, dd = n & 31;
#pragma unroll
    for (int mi = 0; mi < 4; mi++) {
      int mbase = m0 + wm * 64 + mi * 16 + 4 * g;
      int bb = mbase >> 10, rowL = mbase & 1023;
      int bh = bb * 8 + h;
      if (mat < 2) {
        unsigned short* out = (mat == 0) ? qx : kx;
        int m_idx = dd >> 4, hi = (dd >> 3) & 1, j = dd & 7;
#pragma unroll
        for (int r = 0; r < 4; r++) {
          int keyL = rowL + r;
          int ch = keyL >> 5, k32 = keyL & 31;
          out[(((((size_t)bh * 32 + ch) * 3 + m_idx) * 2 + hi) * 32 + k32) * 8 + j] =
              f2bf((acc[mi][ni][r] + bv_) * scale);
        }
      } else {
        int keyL = rowL;
        int ch = keyL >> 5, t = (keyL >> 4) & 1, hi = (keyL >> 3) & 1;
        size_t base = (((((size_t)bh * 32 + ch) * 2 + t) * 2 + hi) * 32 + dd) * 8 + (g & 1) * 4;
        uint2 w2 = make_uint2(pack2(acc[mi][ni][0] + bv_, acc[mi][ni][1] + bv_),
                              pack2(acc[mi][ni][2] + bv_, acc[mi][ni][3] + bv_));
        *(uint2*)&vt2[base] = w2;
      }
    }
  }
}

// ---------------------------------------------------------------------------
// Attention: 32x32x16 MFMA, physics/mask in ext dims, no LDS, no barriers.
// grid (8, 64), 4 waves/block; wave = 32 queries x 1024 keys.
// ---------------------------------------------------------------------------
__global__ __launch_bounds__(256) void attn32(
    const unsigned short* __restrict__ qx, const unsigned short* __restrict__ kx,
    const unsigned short* __restrict__ vt2, unsigned short* __restrict__ ctx) {
  const int tid = threadIdx.x;
  const int wave = tid >> 6, lane = tid & 63;
  const int hi = lane >> 5, l31 = lane & 31;
  const int bh = blockIdx.y, bb = bh >> 3, h = bh & 7;
  const int qch = blockIdx.x * 4 + wave;

  const size_t qoff = (((size_t)(bh * 32 + qch) * 3 * 2 + hi) * 32 + l31) * 8;
  bf16x8 qf0 = *(const bf16x8*)&qx[qoff];
  bf16x8 qf1 = *(const bf16x8*)&qx[qoff + 512];
  bf16x8 qf2 = *(const bf16x8*)&qx[qoff + 1024];

  f32x16 acc = {};
  float mrun = 0.0f, lsum = 0.0f;

  for (int ch = 0; ch < 32; ch++) {
    const size_t koff = (((size_t)(bh * 32 + ch) * 3 * 2 + hi) * 32 + l31) * 8;
    bf16x8 kf0 = *(const bf16x8*)&kx[koff];
    bf16x8 kf1 = *(const bf16x8*)&kx[koff + 512];
    bf16x8 kf2 = *(const bf16x8*)&kx[koff + 1024];
    const size_t voff = (((size_t)(bh * 32 + ch) * 2 * 2 + hi) * 32 + l31) * 8;
    bf16x8 vf0 = *(const bf16x8*)&vt2[voff];
    bf16x8 vf1 = *(const bf16x8*)&vt2[voff + 512];

    f32x16 s = {};
    s = __builtin_amdgcn_mfma_f32_32x32x16_bf16(kf0, qf0, s, 0, 0, 0);
    s = __builtin_amdgcn_mfma_f32_32x32x16_bf16(kf1, qf1, s, 0, 0, 0);
    s = __builtin_amdgcn_mfma_f32_32x32x16_bf16(kf2, qf2, s, 0, 0, 0);

    float pm = fmaxf(fmaxf(fmaxf(s[0], s[1]), fmaxf(s[2], s[3])),
                     fmaxf(fmaxf(s[4], s[5]), fmaxf(s[6], s[7])));
    pm = fmaxf(pm, fmaxf(fmaxf(fmaxf(s[8], s[9]), fmaxf(s[10], s[11])),
                         fmaxf(fmaxf(s[12], s[13]), fmaxf(s[14], s[15]))));
    pm = fmaxf(pm, __shfl_xor(pm, 32, 64));
    if (__any(pm > mrun + 12.0f)) {  // rare: deferred-max rescale
      float mn = fmaxf(mrun, pm);
      float rs = fexp2(mrun - mn);
      lsum *= rs;
      mrun = mn;
#pragma unroll
      for (int r = 0; r < 16; r++) {
        float rr = __shfl(rs, (r & 3) + 8 * (r >> 2) + 4 * hi, 64);
        acc[r] *= rr;
      }
    }
    float p[16];
#pragma unroll
    for (int r = 0; r < 16; r++) p[r] = fexp2(s[r] - mrun);
    lsum += (((p[0] + p[1]) + (p[2] + p[3])) + ((p[4] + p[5]) + (p[6] + p[7]))) +
            (((p[8] + p[9]) + (p[10] + p[11])) + ((p[12] + p[13]) + (p[14] + p[15])));
    unsigned u0 = cvtpk(p[0], p[1]), u1 = cvtpk(p[2], p[3]);
    unsigned u2 = cvtpk(p[4], p[5]), u3 = cvtpk(p[6], p[7]);
    plswap(u0, u2); plswap(u1, u3);
    unsigned u4 = cvtpk(p[8], p[9]), u5 = cvtpk(p[10], p[11]);
    unsigned u6 = cvtpk(p[12], p[13]), u7 = cvtpk(p[14], p[15]);
    plswap(u4, u6); plswap(u5, u7);
    union { unsigned u[4]; bf16x8 v; } A1, A2;
    A1.u[0] = u0; A1.u[1] = u1; A1.u[2] = u2; A1.u[3] = u3;
    A2.u[0] = u4; A2.u[1] = u5; A2.u[2] = u6; A2.u[3] = u7;
    acc = __builtin_amdgcn_mfma_f32_32x32x16_bf16(A1.v, vf0, acc, 0, 0, 0);
    acc = __builtin_amdgcn_mfma_f32_32x32x16_bf16(A2.v, vf1, acc, 0, 0, 0);
  }
  lsum += __shfl_xor(lsum, 32, 64);
  float inv = 1.0f / lsum;
#pragma unroll
  for (int r = 0; r < 16; r++) {
    int qr = (r & 3) + 8 * (r >> 2) + 4 * hi;
    float rr = __shfl(inv, qr, 64);
    ctx[((size_t)bb * 1024 + qch * 32 + qr) * 256 + h * 32 + l31] = f2bf(acc[r] * rr);
  }
}

// ---------------------------------------------------------------------------
// Generic bf16 GEMM, BM = MIN*32, BN=128. C = A @ W^T + bias (+epilogue).
// EPI=1: f32 out = acc+bias+resid_f32. EPI=2: bf16 out = gelu(acc+bias).
// EPI=3: f32 out = acc+bias+resid_bf16.
// ---------------------------------------------------------------------------
template <int EPI, int MIN>
__global__ __launch_bounds__(256) void gemm_bf(
    const unsigned short* __restrict__ A, const unsigned short* __restrict__ W,
    const float* __restrict__ bias, const void* __restrict__ resid,
    void* __restrict__ Cout, int N, int K) {
  constexpr int BM = MIN * 32;
  __shared__ __align__(16) unsigned short As[BM * 64];
  __shared__ __align__(16) unsigned short Bs[128 * 64];
  const int tid = threadIdx.x;
  const int n0 = blockIdx.x * 128;
  const int m0 = blockIdx.y * BM;
  const int wm = (tid >> 7) & 1, wn = (tid >> 6) & 1;
  const int g = (tid >> 4) & 3, c = tid & 15;
  f32x4 acc[MIN][4] = {};
  for (int k0 = 0; k0 < K; k0 += 64) {
    __syncthreads();
#pragma unroll
    for (int i = 0; i < MIN; i++) {
      int idx = tid * 8 + i * 2048;
      int r = idx >> 6, c8 = idx & 63;
      bf16x8 va = *(const bf16x8*)&A[(size_t)(m0 + r) * K + k0 + c8];
      *(bf16x8*)&As[r * 64 + (((c8 >> 3) ^ (r & 7)) << 3)] = va;
    }
#pragma unroll
    for (int i = 0; i < 4; i++) {
      int idx = tid * 8 + i * 2048;
      int r = idx >> 6, c8 = idx & 63;
      bf16x8 vb = *(const bf16x8*)&W[(size_t)(n0 + r) * K + k0 + c8];
      *(bf16x8*)&Bs[r * 64 + (((c8 >> 3) ^ (r & 7)) << 3)] = vb;
    }
    __syncthreads();
#pragma unroll
    for (int kk = 0; kk < 2; kk++) {
      bf16x8 af[MIN], bfr[4];
#pragma unroll
      for (int mi = 0; mi < MIN; mi++) {
        int row = wm * (MIN * 16) + mi * 16 + c;
        af[mi] = *(const bf16x8*)&As[row * 64 + (((g + 4 * kk) ^ (row & 7)) << 3)];
      }
#pragma unroll
      for (int ni = 0; ni < 4; ni++) {
        int row = wn * 64 + ni * 16 + c;
        bfr[ni] = *(const bf16x8*)&Bs[row * 64 + (((g + 4 * kk) ^ (row & 7)) << 3)];
      }
#pragma unroll
      for (int mi = 0; mi < MIN; mi++)
#pragma unroll
        for (int ni = 0; ni < 4; ni++)
          acc[mi][ni] = __builtin_amdgcn_mfma_f32_16x16x32_bf16(af[mi], bfr[ni], acc[mi][ni], 0, 0, 0);
    }
  }
#pragma unroll
  for (int ni = 0; ni < 4; ni++) {
    int n = n0 + wn * 64 + ni * 16 + c;
    float bv_ = bias[n];
#pragma unroll
    for (int mi = 0; mi < MIN; mi++) {
      int mbase = m0 + wm * (MIN * 16) + mi * 16 + 4 * g;
#pragma unroll
      for (int r = 0; r < 4; r++) {
        int m = mbase + r;
        float x = acc[mi][ni][r] + bv_;
        if constexpr (EPI == 1) {
          ((float*)Cout)[(size_t)m * N + n] = x + ((const float*)resid)[(size_t)m * N + n];
        } else if constexpr (EPI == 2) {
          ((unsigned short*)Cout)[(size_t)m * N + n] =
              f2bf(x * 0.5f * (1.0f + erff(x * 0.70710678118654752f)));
        } else {
          ((float*)Cout)[(size_t)m * N + n] =
              x + bf2f(((const unsigned short*)resid)[(size_t)m * N + n]);
        }
      }
    }
  }
}

// ---------------------------------------------------------------------------
// LayerNorm over D=256 per row. OUTBF: bf16 output, else f32.
// ---------------------------------------------------------------------------
template <int OUTBF>
__global__ __launch_bounds__(256) void ln_kernel(const float* __restrict__ x,
                                                 const float* __restrict__ g,
                                                 const float* __restrict__ b,
                                                 void* __restrict__ y) {
  const int row = blockIdx.x, t = threadIdx.x;
  const float v = x[(size_t)row * 256 + t];
  float s1 = v, s2 = v * v;
#pragma unroll
  for (int o = 1; o < 64; o <<= 1) {
    s1 += __shfl_xor(s1, o, 64);
    s2 += __shfl_xor(s2, o, 64);
  }
  __shared__ float w1[4], w2[4];
  if ((t & 63) == 0) { w1[t >> 6] = s1; w2[t >> 6] = s2; }
  __syncthreads();
  float ts1 = w1[0] + w1[1] + w1[2] + w1[3];
  float ts2 = w2[0] + w2[1] + w2[2] + w2[3];
  float mean = ts1 * (1.0f / 256.0f);
  float var = fmaxf(ts2 * (1.0f / 256.0f) - mean * mean, 0.0f);
  float out = (v - mean) * rsqrtf(var + 1e-12f) * g[t] + b[t];
  if constexpr (OUTBF)
    ((unsigned short*)y)[(size_t)row * 256 + t] = f2bf(out);
  else
    ((float*)y)[(size_t)row * 256 + t] = out;
}

// ---------------------------------------------------------------------------
extern "C" void kernel_launch(void* const* d_in, const int* in_sizes, int n_in,
                              void* d_out, int out_size, void* d_ws,
                              size_t ws_size, hipStream_t stream) {
  const float* hs = (const float*)d_in[0];
  const float* mask = (const float*)d_in[1];
  const float* phi = (const float*)d_in[2];
  const float* mag = (const float*)d_in[3];
  const float* Wq = (const float*)d_in[4];
  const float* bq = (const float*)d_in[5];
  const float* Wk = (const float*)d_in[6];
  const float* bk = (const float*)d_in[7];
  const float* Wv = (const float*)d_in[8];
  const float* bv = (const float*)d_in[9];
  const float* Wo = (const float*)d_in[10];
  const float* bo = (const float*)d_in[11];
  const float* ln1g = (const float*)d_in[12];
  const float* ln1b = (const float*)d_in[13];
  const float* gamma = (const float*)d_in[14];
  const float* W1 = (const float*)d_in[15];
  const float* b1 = (const float*)d_in[16];
  const float* W2 = (const float*)d_in[17];
  const float* b2 = (const float*)d_in[18];
  const float* ln2g = (const float*)d_in[19];
  const float* ln2b = (const float*)d_in[20];

  char* wsb = (char*)d_ws;
  unsigned short* wts = (unsigned short*)(wsb + 0);            // 1.5MB
  unsigned short* hsb = (unsigned short*)(wsb + (2ull << 20)); // 4MB
  unsigned short* ctx = (unsigned short*)(wsb + (6ull << 20)); // 4MB
  float* tmp = (float*)(wsb + (10ull << 20));                  // 8MB
  unsigned short* aout = (unsigned short*)(wsb + (18ull << 20)); // 4MB
  unsigned short* qx = (unsigned short*)(wsb + (22ull << 20)); // 6MB
  unsigned short* kx = (unsigned short*)(wsb + (28ull << 20)); // 6MB
  unsigned short* vt2 = (unsigned short*)(wsb + (34ull << 20)); // 4MB
  unsigned short* hbuf = (unsigned short*)(wsb + (22ull << 20)); // 16MB (reuse qx/kx/vt2)

  dim3 blk(256);
  prep_kernel<<<dim3(2048), blk, 0, stream>>>(hs, phi, mag, mask, gamma, Wq, Wk,
                                              Wv, Wo, W1, W2, wts, hsb, qx, kx);
  gemm_qkv<<<dim3(6, 64), blk, 0, stream>>>(hsb, wts, bq, bk, bv, qx, kx, vt2);
  attn32<<<dim3(8, 64), blk, 0, stream>>>(qx, kx, vt2, ctx);
  gemm_bf<1, 2><<<dim3(2, 128), blk, 0, stream>>>(ctx, wts + 196608, bo, hs, tmp, 256, 256);
  ln_kernel<1><<<dim3(8192), blk, 0, stream>>>(tmp, ln1g, ln1b, aout);
  gemm_bf<2, 4><<<dim3(8, 64), blk, 0, stream>>>(aout, wts + 262144, b1, nullptr, hbuf, 1024, 256);
  gemm_bf<3, 2><<<dim3(2, 128), blk, 0, stream>>>(hbuf, wts + 524288, b2, aout, tmp, 256, 1024);
  ln_kernel<0><<<dim3(8192), blk, 0, stream>>>(tmp, ln2g, ln2b, d_out);
}